// Round 1
// baseline (1129.480 us; speedup 1.0000x reference)
//
#include <hip/hip_runtime.h>

// ROI pooling (crop + bilinear resize to 7x7), NHWC, C=256.
// img: (1,1024,1024,256) f32, rois: (1,300,4) f32 {x,y,w,h} (integer-valued)
// out: (1,300,7,7,256) f32
//
// One wave (64 threads) per (roi,py,px). Lane i handles channels [4i,4i+4):
// 4 coalesced float4 corner loads -> bilinear blend -> 1 float4 store.

#define IMG_H 1024
#define IMG_W 1024
#define IMG_C 256
#define POOLP 7
#define NROIS 300

__global__ __launch_bounds__(64) void roi_pool_kernel(
    const float* __restrict__ img,
    const float* __restrict__ rois,
    float* __restrict__ out)
{
    const int b  = blockIdx.x;          // r*49 + py*7 + px
    const int r  = b / 49;
    const int t  = b - r * 49;
    const int py = t / 7;
    const int px = t - py * 7;

    // ROI box (values are non-negative integers stored as float)
    const float4 rv = ((const float4*)rois)[r];
    const int x0 = (int)rv.x;
    const int y0 = (int)rv.y;
    const int w  = (int)rv.z;
    const int h  = (int)rv.w;
    const float wf = (float)w;
    const float hf = (float)h;

    // Half-pixel-center sample coords, clamped to the crop (matches reference)
    float cy = ((float)py + 0.5f) * (hf / 7.0f) - 0.5f;
    cy = fminf(fmaxf(cy, 0.0f), hf - 1.0f);
    const int   ylo = (int)floorf(cy);
    const int   yhi = min(ylo + 1, h - 1);
    const float fy  = cy - (float)ylo;

    float cx = ((float)px + 0.5f) * (wf / 7.0f) - 0.5f;
    cx = fminf(fmaxf(cx, 0.0f), wf - 1.0f);
    const int   xlo = (int)floorf(cx);
    const int   xhi = min(xlo + 1, w - 1);
    const float fx  = cx - (float)xlo;

    const size_t rowlo = (size_t)(y0 + ylo) * IMG_W;
    const size_t rowhi = (size_t)(y0 + yhi) * IMG_W;
    const float4* __restrict__ p00 = (const float4*)(img + (rowlo + (size_t)(x0 + xlo)) * IMG_C);
    const float4* __restrict__ p01 = (const float4*)(img + (rowlo + (size_t)(x0 + xhi)) * IMG_C);
    const float4* __restrict__ p10 = (const float4*)(img + (rowhi + (size_t)(x0 + xlo)) * IMG_C);
    const float4* __restrict__ p11 = (const float4*)(img + (rowhi + (size_t)(x0 + xhi)) * IMG_C);

    const int c4 = threadIdx.x;         // 0..63, channels 4*c4 .. 4*c4+3
    const float4 v00 = p00[c4];
    const float4 v01 = p01[c4];
    const float4 v10 = p10[c4];
    const float4 v11 = p11[c4];

    const float gx = 1.0f - fx;
    const float gy = 1.0f - fy;

    float4 o;
    o.x = (v00.x * gx + v01.x * fx) * gy + (v10.x * gx + v11.x * fx) * fy;
    o.y = (v00.y * gx + v01.y * fx) * gy + (v10.y * gx + v11.y * fx) * fy;
    o.z = (v00.z * gx + v01.z * fx) * gy + (v10.z * gx + v11.z * fx) * fy;
    o.w = (v00.w * gx + v01.w * fx) * gy + (v10.w * gx + v11.w * fx) * fy;

    ((float4*)out)[(size_t)b * 64 + c4] = o;
}

extern "C" void kernel_launch(void* const* d_in, const int* in_sizes, int n_in,
                              void* d_out, int out_size, void* d_ws, size_t ws_size,
                              hipStream_t stream)
{
    const float* img  = (const float*)d_in[0];   // 1*1024*1024*256
    const float* rois = (const float*)d_in[1];   // 1*300*4
    float* out = (float*)d_out;                  // 300*7*7*256

    const int nblocks = NROIS * POOLP * POOLP;   // 14700
    roi_pool_kernel<<<nblocks, 64, 0, stream>>>(img, rois, out);
}